// Round 2
// baseline (1203.053 us; speedup 1.0000x reference)
//
#include <hip/hip_runtime.h>
#include <hip/hip_bf16.h>

#define S_LEN 2048
#define HIDDEN 2048
#define NHEAD 16
#define NKVH 4
#define HEADD 128
#define BATCH 2

typedef __attribute__((ext_vector_type(4))) float f32x4;
typedef __attribute__((ext_vector_type(8))) short bf16x8;
typedef __attribute__((ext_vector_type(4))) unsigned short u16x4;

__device__ __forceinline__ unsigned short f2bf(float f) {
  union { __hip_bfloat16 h; unsigned short u; } cv;
  cv.h = __float2bfloat16(f);
  return cv.u;
}

__device__ __forceinline__ void gl_lds16(const void* g, void* l) {
  __builtin_amdgcn_global_load_lds(
      (const __attribute__((address_space(1))) unsigned int*)g,
      (__attribute__((address_space(3))) unsigned int*)l,
      16, 0, 0);
}

// ---------------- rope table: [S][64] {cos,sin} ----------------
__global__ void k_rope_table(float* tab) {
  int idx = blockIdx.x * blockDim.x + threadIdx.x;
  if (idx >= S_LEN * 64) return;
  int s = idx >> 6, j = idx & 63;
  float invf = expf(-(float)j * (logf(10000.0f) / 64.0f));
  float ang = (float)s * invf;
  float sn, cs;
  sincosf(ang, &sn, &cs);
  tab[idx * 2 + 0] = cs;
  tab[idx * 2 + 1] = sn;
}

// ---------------- pack X = [xr|xi] -> bf16 [4096][4096] ----------------
__global__ void k_pack_x(const float* __restrict__ xr, const float* __restrict__ xi,
                         unsigned short* __restrict__ Xp) {
  int idx = blockIdx.x * blockDim.x + threadIdx.x;  // over float4 chunks
  if (idx >= 4096 * 4096 / 4) return;
  int m = idx >> 10;          // 1024 chunks per row
  int c4 = idx & 1023;
  const float* src = (c4 < 512) ? (xr + (size_t)m * 2048 + c4 * 4)
                                : (xi + (size_t)m * 2048 + (c4 - 512) * 4);
  f32x4 v = *(const f32x4*)src;
  ((u16x4*)Xp)[idx] = (u16x4){f2bf(v.x), f2bf(v.y), f2bf(v.z), f2bf(v.w)};
}

// ---------------- pack weights transposed bf16: Wt[n][k], n in [0,10240) ----------------
__global__ void k_pack_w(const float* __restrict__ wq_r, const float* __restrict__ wq_i,
                         const float* __restrict__ wk_r, const float* __restrict__ wk_i,
                         const float* __restrict__ wv_r, const float* __restrict__ wv_i,
                         const float* __restrict__ wo_r, const float* __restrict__ wo_i,
                         unsigned short* __restrict__ Wt) {
  __shared__ float tile[32][33];
  int k0 = blockIdx.x * 32;
  int n0 = blockIdx.y * 32;
  int tx = threadIdx.x, ty0 = threadIdx.y;
#pragma unroll
  for (int i = 0; i < 4; ++i) {
    int ty = ty0 + i * 8;
    int k = k0 + ty;
    int n = n0 + tx;
    const float* Wr; const float* Wi; int w, t, part, j;
    if (n < 4096)      { Wr = wq_r; Wi = wq_i; w = 2048; t = n;        }
    else if (n < 5120) { Wr = wk_r; Wi = wk_i; w = 512;  t = n - 4096; }
    else if (n < 6144) { Wr = wv_r; Wi = wv_i; w = 512;  t = n - 5120; }
    else               { Wr = wo_r; Wi = wo_i; w = 2048; t = n - 6144; }
    part = (t >= w); j = part ? (t - w) : t;
    float v;
    if (part == 0) v = (k < 2048) ? Wr[(size_t)k * w + j] : -Wi[(size_t)(k - 2048) * w + j];
    else           v = (k < 2048) ? Wi[(size_t)k * w + j] :  Wr[(size_t)(k - 2048) * w + j];
    tile[ty][tx] = v;
  }
  __syncthreads();
#pragma unroll
  for (int i = 0; i < 4; ++i) {
    int ty = ty0 + i * 8;
    Wt[(size_t)(n0 + ty) * 4096 + k0 + tx] = f2bf(tile[tx][ty]);
  }
}

// ---------------- generic bf16 MFMA GEMM: C[M,N] = A[M,K] @ Bt[N,K]^T ----------------
// mode 0: plain f32 store to Cout (ldc)
// mode 1: O-proj epilogue: split r/i + bias -> outR/outI [4096][2048]
// mode 2: scores per-z (b,h): raw scaled scores + per-block row (max, sumexp) partials
__global__ __launch_bounds__(256) void k_gemm(
    const unsigned short* __restrict__ Aall, int lda,
    const unsigned short* __restrict__ Ball, int ldb,
    float* __restrict__ Cout, int ldc, int K, int mode,
    float* __restrict__ outR, float* __restrict__ outI,
    const float* __restrict__ bR, const float* __restrict__ bI,
    float2* __restrict__ part) {
  __shared__ __align__(16) unsigned short sA[128 * 32];
  __shared__ __align__(16) unsigned short sB[128 * 32];
  __shared__ float sPart[2][128][2];
  int tid = threadIdx.x, lane = tid & 63, wid = tid >> 6;
  int n0 = blockIdx.x * 128, m0 = blockIdx.y * 128;
  const unsigned short* A = Aall;
  const unsigned short* Bt = Ball;
  float* Cp = Cout;
  int bh = blockIdx.z;
  if (mode == 2) {
    int b = bh >> 4, h = bh & 15;
    A = Aall + (size_t)bh * S_LEN * 256;
    Bt = Ball + (size_t)(b * NKVH + (h >> 2)) * S_LEN * 256;
    Cp = Cout + (size_t)bh * S_LEN * S_LEN;
    if (n0 >= m0 + 128) {  // fully masked tile: zero probs + neutral partials
      const f32x4 z = {0.f, 0.f, 0.f, 0.f};
#pragma unroll
      for (int i = 0; i < 16; ++i) {
        int c = tid + 256 * i;
        int r = c >> 5, cc = c & 31;
        *(f32x4*)(Cp + (size_t)(m0 + r) * S_LEN + n0 + cc * 4) = z;
      }
      if (tid < 128)
        part[((size_t)bh * S_LEN + m0 + tid) * 16 + (n0 >> 7)] = make_float2(-1e30f, 0.f);
      return;
    }
  }
  int wr = wid >> 1, wc = wid & 1;
  const f32x4 fz = {0.f, 0.f, 0.f, 0.f};
  f32x4 acc[4][4];
#pragma unroll
  for (int i = 0; i < 4; ++i)
#pragma unroll
    for (int j = 0; j < 4; ++j) acc[i][j] = fz;

  const char* Abase = (const char*)A + (size_t)m0 * lda * 2;
  const char* Bbase = (const char*)Bt + (size_t)n0 * ldb * 2;
  for (int k0 = 0; k0 < K; k0 += 32) {
    __syncthreads();
    {
      int c0 = tid, c1 = tid + 256;
      const char* Ab = Abase + (size_t)k0 * 2;
      const char* Bb = Bbase + (size_t)k0 * 2;
      gl_lds16(Ab + (size_t)(c0 >> 2) * lda * 2 + (c0 & 3) * 16, (char*)sA + wid * 1024);
      gl_lds16(Ab + (size_t)(c1 >> 2) * lda * 2 + (c1 & 3) * 16, (char*)sA + 4096 + wid * 1024);
      gl_lds16(Bb + (size_t)(c0 >> 2) * ldb * 2 + (c0 & 3) * 16, (char*)sB + wid * 1024);
      gl_lds16(Bb + (size_t)(c1 >> 2) * ldb * 2 + (c1 & 3) * 16, (char*)sB + 4096 + wid * 1024);
    }
    __syncthreads();
    const char* aw = (const char*)sA + wr * 64 * 64;
    const char* bw = (const char*)sB + wc * 64 * 64;
    int lrow = lane & 15, lkb = (lane >> 4) * 16;
    bf16x8 af[4], bfr[4];
#pragma unroll
    for (int i = 0; i < 4; ++i) af[i] = *(const bf16x8*)(aw + (i * 16 + lrow) * 64 + lkb);
#pragma unroll
    for (int i = 0; i < 4; ++i) bfr[i] = *(const bf16x8*)(bw + (i * 16 + lrow) * 64 + lkb);
#pragma unroll
    for (int i = 0; i < 4; ++i)
#pragma unroll
      for (int j = 0; j < 4; ++j)
        acc[i][j] = __builtin_amdgcn_mfma_f32_16x16x32_bf16(af[i], bfr[j], acc[i][j], 0, 0, 0);
  }
  int r0 = (lane >> 4) * 4, col = lane & 15;
  if (mode == 2) {
    const float scale = 0.08838834764831845f;  // 1/sqrt(128)
#pragma unroll
    for (int i = 0; i < 4; ++i) {
#pragma unroll
      for (int r = 0; r < 4; ++r) {
        int lr = wr * 64 + i * 16 + r0 + r;
        int gm = m0 + lr;
        float vv[4];
        float lm = -1e30f;
#pragma unroll
        for (int j = 0; j < 4; ++j) {
          int gn = n0 + wc * 64 + j * 16 + col;
          float v = acc[i][j][r] * scale;
          vv[j] = v;
          Cp[(size_t)gm * S_LEN + gn] = v;   // raw score (PV re-masks by index)
          if (gn <= gm) lm = fmaxf(lm, v);
        }
#pragma unroll
        for (int o = 1; o < 16; o <<= 1) lm = fmaxf(lm, __shfl_xor(lm, o));
        float ls = 0.f;
#pragma unroll
        for (int j = 0; j < 4; ++j) {
          int gn = n0 + wc * 64 + j * 16 + col;
          if (gn <= gm) ls += __expf(vv[j] - lm);
        }
#pragma unroll
        for (int o = 1; o < 16; o <<= 1) ls += __shfl_xor(ls, o);
        if (col == 0) { sPart[wc][lr][0] = lm; sPart[wc][lr][1] = ls; }
      }
    }
    __syncthreads();
    if (tid < 128) {
      float ma = sPart[0][tid][0], mb = sPart[1][tid][0];
      float la = sPart[0][tid][1], lb = sPart[1][tid][1];
      float m = fmaxf(ma, mb);
      float l = la * __expf(ma - m) + lb * __expf(mb - m);
      part[((size_t)bh * S_LEN + m0 + tid) * 16 + (n0 >> 7)] = make_float2(m, l);
    }
    return;
  }
#pragma unroll
  for (int i = 0; i < 4; ++i)
#pragma unroll
    for (int j = 0; j < 4; ++j) {
      int gmb = m0 + wr * 64 + i * 16 + r0;
      int gn = n0 + wc * 64 + j * 16 + col;
#pragma unroll
      for (int r = 0; r < 4; ++r) {
        float v = acc[i][j][r];
        int gm = gmb + r;
        if (mode == 0) {
          Cp[(size_t)gm * ldc + gn] = v;
        } else {
          if (gn < 2048) outR[(size_t)gm * 2048 + gn] = v + bR[gn];
          else           outI[(size_t)gm * 2048 + (gn - 2048)] = v + bI[gn - 2048];
        }
      }
    }
}

// ---------------- combine partials -> (m, 1/l) per row ----------------
__global__ void k_combine(const float2* __restrict__ part, float2* __restrict__ minv) {
  int idx = blockIdx.x * blockDim.x + threadIdx.x;  // 32*2048
  if (idx >= 32 * S_LEN) return;
  const float2* p = part + (size_t)idx * 16;
  float m = -1e30f;
#pragma unroll
  for (int i = 0; i < 16; ++i) m = fmaxf(m, p[i].x);
  float l = 0.f;
#pragma unroll
  for (int i = 0; i < 16; ++i) l += p[i].y * __expf(p[i].x - m);
  minv[idx] = make_float2(m, 1.0f / l);
}

// ---------------- rope + pack Q: Qcat[b,h][s][256] bf16 ----------------
__global__ void k_rope_q(const float* __restrict__ QKVf, const float* __restrict__ tab,
                         const float* __restrict__ bqr, const float* __restrict__ bqi,
                         unsigned short* __restrict__ Qcat) {
  int idx = blockIdx.x * blockDim.x + threadIdx.x;  // B*S*NH*HD = 8388608
  if (idx >= BATCH * S_LEN * NHEAD * HEADD) return;
  int d = idx & 127;
  int h = (idx >> 7) & 15;
  int s = (idx >> 11) & 2047;
  int b = (idx >> 22) & 1;
  size_t m = (size_t)b * S_LEN + s;
  int colc = h * 128 + d;
  float qr = QKVf[m * 6144 + colc] + bqr[colc];
  float qi = QKVf[m * 6144 + 2048 + colc] + bqi[colc];
  int ti = (s * 64 + (d & 63)) * 2;
  float cs = tab[ti], sn = tab[ti + 1];
  float orr = qr * cs - qi * sn;
  float oii = qr * sn + qi * cs;
  size_t base = ((size_t)(b * NHEAD + h) * S_LEN + s) * 256;
  Qcat[base + d] = f2bf(orr);
  Qcat[base + 128 + d] = f2bf(oii);
}

// ---------------- rope + pack K: Kcat[b,kv][s][256] bf16 ----------------
__global__ void k_rope_k(const float* __restrict__ QKVf, const float* __restrict__ tab,
                         const float* __restrict__ bkr, const float* __restrict__ bki,
                         unsigned short* __restrict__ Kcat) {
  int idx = blockIdx.x * blockDim.x + threadIdx.x;  // B*S*NKV*HD = 2097152
  if (idx >= BATCH * S_LEN * NKVH * HEADD) return;
  int d = idx & 127;
  int kv = (idx >> 7) & 3;
  int s = (idx >> 9) & 2047;
  int b = (idx >> 20) & 1;
  size_t m = (size_t)b * S_LEN + s;
  int jb = kv * 128 + d;
  float kr = QKVf[m * 6144 + 4096 + jb] + bkr[jb];
  float ki = QKVf[m * 6144 + 4608 + jb] + bki[jb];
  int ti = (s * 64 + (d & 63)) * 2;
  float cs = tab[ti], sn = tab[ti + 1];
  float orr = kr * cs - ki * sn;
  float oii = kr * sn + ki * cs;
  size_t base = ((size_t)(b * NKVH + kv) * S_LEN + s) * 256;
  Kcat[base + d] = f2bf(orr);
  Kcat[base + 128 + d] = f2bf(oii);
}

// ---------------- V pack transposed: Vt[b,kv][256][2048] bf16 ----------------
__global__ void k_vpack(const float* __restrict__ QKVf, const float* __restrict__ bvr,
                        const float* __restrict__ bvi, unsigned short* __restrict__ Vt) {
  __shared__ float tile[32][33];
  int s0 = blockIdx.x * 32, n0 = blockIdx.y * 32, bkv = blockIdx.z;
  int b = bkv >> 2, kv = bkv & 3;
  int tx = threadIdx.x, ty0 = threadIdx.y;
#pragma unroll
  for (int i = 0; i < 4; ++i) {
    int ty = ty0 + i * 8;
    int s = s0 + ty, n = n0 + tx;
    int d = n & 127, isI = n >> 7;
    int col = (isI ? 5632 : 5120) + kv * 128 + d;
    float bias = isI ? bvi[kv * 128 + d] : bvr[kv * 128 + d];
    tile[ty][tx] = QKVf[(size_t)(b * S_LEN + s) * 6144 + col] + bias;
  }
  __syncthreads();
#pragma unroll
  for (int i = 0; i < 4; ++i) {
    int ty = ty0 + i * 8;
    Vt[(size_t)(bkv * 256 + n0 + ty) * S_LEN + s0 + tx] = f2bf(tile[tx][ty]);
  }
}

// ---------------- fused normalize + PV: reads raw S once, writes P + Cpack ----------------
__global__ __launch_bounds__(512) void k_pv_fused(
    float* __restrict__ attn, const unsigned short* __restrict__ Vt,
    const float2* __restrict__ minv, unsigned short* __restrict__ Cpack) {
  __shared__ __align__(16) unsigned short sA[128 * 32];
  __shared__ __align__(16) unsigned short sB[256 * 32];
  __shared__ float sM[128], sI[128];
  int tid = threadIdx.x, lane = tid & 63, wid = tid >> 6;
  int qt = blockIdx.x;     // 0..15
  int bh = blockIdx.y;     // 0..31
  int b = bh >> 4, h = bh & 15;
  int m0 = qt * 128;
  float* P = attn + (size_t)bh * S_LEN * S_LEN;
  const unsigned short* V = Vt + (size_t)(b * NKVH + (h >> 2)) * 256 * S_LEN;
  if (tid < 128) {
    float2 ml = minv[(size_t)bh * S_LEN + m0 + tid];
    sM[tid] = ml.x;
    sI[tid] = ml.y;
  }
  int wr = wid >> 2, wc = wid & 3;
  const f32x4 fz = {0.f, 0.f, 0.f, 0.f};
  f32x4 acc[4][4];
#pragma unroll
  for (int i = 0; i < 4; ++i)
#pragma unroll
    for (int j = 0; j < 4; ++j) acc[i][j] = fz;
  int kmax = m0 + 128;
  for (int k0 = 0; k0 < kmax; k0 += 32) {
    __syncthreads();
    // stage P (normalize, mask, write back final probs, bf16 -> sA)
#pragma unroll
    for (int ii = 0; ii < 2; ++ii) {
      int c = tid + 512 * ii;  // 1024 chunks of 4 floats
      int row = c >> 3, cc = c & 7;
      float* pp = P + (size_t)(m0 + row) * S_LEN + k0 + cc * 4;
      f32x4 v = *(const f32x4*)pp;
      float m = sM[row], inv = sI[row];
      int q = m0 + row, kb = k0 + cc * 4;
      f32x4 o;
      o.x = (kb + 0 <= q) ? __expf(v.x - m) * inv : 0.f;
      o.y = (kb + 1 <= q) ? __expf(v.y - m) * inv : 0.f;
      o.z = (kb + 2 <= q) ? __expf(v.z - m) * inv : 0.f;
      o.w = (kb + 3 <= q) ? __expf(v.w - m) * inv : 0.f;
      *(f32x4*)pp = o;
      *(u16x4*)((char*)sA + row * 64 + cc * 8) =
          (u16x4){f2bf(o.x), f2bf(o.y), f2bf(o.z), f2bf(o.w)};
    }
    // stage V (256 rows x 32 cols bf16)
    {
      const char* Bb = (const char*)V + (size_t)k0 * 2;
      int c0 = tid, c1 = tid + 512;
      gl_lds16(Bb + (size_t)(c0 >> 2) * S_LEN * 2 + (c0 & 3) * 16, (char*)sB + c0 * 16);
      gl_lds16(Bb + (size_t)(c1 >> 2) * S_LEN * 2 + (c1 & 3) * 16, (char*)sB + c1 * 16);
    }
    __syncthreads();
    int lrow = lane & 15, lkb = (lane >> 4) * 16;
    bf16x8 af[4], bfr[4];
#pragma unroll
    for (int i = 0; i < 4; ++i)
      af[i] = *(const bf16x8*)((char*)sA + (wr * 64 + i * 16 + lrow) * 64 + lkb);
#pragma unroll
    for (int j = 0; j < 4; ++j)
      bfr[j] = *(const bf16x8*)((char*)sB + (wc * 64 + j * 16 + lrow) * 64 + lkb);
#pragma unroll
    for (int i = 0; i < 4; ++i)
#pragma unroll
      for (int j = 0; j < 4; ++j)
        acc[i][j] = __builtin_amdgcn_mfma_f32_16x16x32_bf16(af[i], bfr[j], acc[i][j], 0, 0, 0);
  }
  int r0 = (lane >> 4) * 4, col = lane & 15;
#pragma unroll
  for (int i = 0; i < 4; ++i)
#pragma unroll
    for (int j = 0; j < 4; ++j) {
      int gmb = m0 + wr * 64 + i * 16 + r0;
      int nn = wc * 64 + j * 16 + col;
      int gcol = (nn < 128) ? (h * 128 + nn) : (2048 + h * 128 + (nn - 128));
#pragma unroll
      for (int r = 0; r < 4; ++r) {
        int gm = gmb + r;
        Cpack[(size_t)(b * S_LEN + gm) * 4096 + gcol] = f2bf(acc[i][j][r]);
      }
    }
}

extern "C" void kernel_launch(void* const* d_in, const int* in_sizes, int n_in,
                              void* d_out, int out_size, void* d_ws, size_t ws_size,
                              hipStream_t stream) {
  const float* xr = (const float*)d_in[0];
  const float* xi = (const float*)d_in[1];
  const float* wq_r = (const float*)d_in[2];
  const float* wq_i = (const float*)d_in[3];
  const float* bq_r = (const float*)d_in[4];
  const float* bq_i = (const float*)d_in[5];
  const float* wk_r = (const float*)d_in[6];
  const float* wk_i = (const float*)d_in[7];
  const float* bk_r = (const float*)d_in[8];
  const float* bk_i = (const float*)d_in[9];
  const float* wv_r = (const float*)d_in[10];
  const float* wv_i = (const float*)d_in[11];
  const float* bv_r = (const float*)d_in[12];
  const float* bv_i = (const float*)d_in[13];
  const float* wo_r = (const float*)d_in[14];
  const float* wo_i = (const float*)d_in[15];
  const float* bo_r = (const float*)d_in[16];
  const float* bo_i = (const float*)d_in[17];

  float* out = (float*)d_out;
  float* outR = out;
  float* outI = out + (size_t)BATCH * S_LEN * HIDDEN;
  float* attn = outI + (size_t)BATCH * S_LEN * HIDDEN;

  char* ws = (char*)d_ws;
  size_t off = 0;
  auto alloc = [&](size_t bytes) {
    char* p = ws + off;
    off += (bytes + 255) & ~(size_t)255;
    return p;
  };
  unsigned short* Xp = (unsigned short*)alloc((size_t)4096 * 4096 * 2);
  unsigned short* Wt = (unsigned short*)alloc((size_t)10240 * 4096 * 2);
  float* QKVf = (float*)alloc((size_t)4096 * 6144 * 4);
  float* tab = (float*)alloc((size_t)S_LEN * 64 * 2 * 4);
  unsigned short* Qcat = (unsigned short*)alloc((size_t)BATCH * NHEAD * S_LEN * 256 * 2);
  unsigned short* Kcat = (unsigned short*)alloc((size_t)BATCH * NKVH * S_LEN * 256 * 2);
  unsigned short* Vt = (unsigned short*)alloc((size_t)BATCH * NKVH * 256 * S_LEN * 2);
  float2* part = (float2*)alloc((size_t)32 * S_LEN * 16 * sizeof(float2));
  float2* minv = (float2*)alloc((size_t)32 * S_LEN * sizeof(float2));
  unsigned short* Cpack = Xp;  // reuse: Xp dead after QKV GEMM

  k_rope_table<<<512, 256, 0, stream>>>(tab);
  k_pack_x<<<16384, 256, 0, stream>>>(xr, xi, Xp);
  k_pack_w<<<dim3(128, 320), dim3(32, 8), 0, stream>>>(wq_r, wq_i, wk_r, wk_i, wv_r, wv_i,
                                                       wo_r, wo_i, Wt);
  // QKV fused GEMM: [4096,4096] @ [4096,6144]
  k_gemm<<<dim3(48, 32, 1), 256, 0, stream>>>(Xp, 4096, Wt, 4096, QKVf, 6144, 4096, 0,
                                              nullptr, nullptr, nullptr, nullptr, nullptr);
  k_rope_q<<<32768, 256, 0, stream>>>(QKVf, tab, bq_r, bq_i, Qcat);
  k_rope_k<<<8192, 256, 0, stream>>>(QKVf, tab, bk_r, bk_i, Kcat);
  k_vpack<<<dim3(64, 8, 8), dim3(32, 8), 0, stream>>>(QKVf, bv_r, bv_i, Vt);
  // scores: per (b,h) [2048,256] @ [2048,256]^T, raw scaled scores + row partials
  k_gemm<<<dim3(16, 16, 32), 256, 0, stream>>>(Qcat, 256, Kcat, 256, attn, 0, 256, 2,
                                               nullptr, nullptr, nullptr, nullptr, part);
  k_combine<<<256, 256, 0, stream>>>(part, minv);
  // fused normalize + PV (writes final probs + packed context)
  k_pv_fused<<<dim3(16, 32), 512, 0, stream>>>(attn, Vt, minv, Cpack);
  // O proj: [4096,4096] @ [4096,4096], split epilogue with bias
  k_gemm<<<dim3(32, 32, 1), 256, 0, stream>>>(Cpack, 4096, Wt + (size_t)6144 * 4096, 4096,
                                              nullptr, 0, 4096, 1, outR, outI, bo_r, bo_i,
                                              nullptr);
}